// Round 5
// baseline (158.019 us; speedup 1.0000x reference)
//
#include <hip/hip_runtime.h>
#include <hip/hip_bf16.h>
#include <math.h>

// out[i,f] = tanh(b[f] + a[f] * dot(W[f,:], x[i,:]))
// GEMM M=32768 N=512 K=512, A=x row-major [M,K], B=W row-major [N,K] (B^T layout).
// fp32 via 3-term bf16 split (RNE + exact residual): z = xh*Wh + xh*Wl + xl*Wh.
//
// Two-kernel plan (if ws_size >= 1MB, else fallback to in-kernel W split):
//   1. split_w: W fp32 -> Whi/Wlo bf16 row-major in d_ws (1 MB).
//   2. gemm: A split in-kernel (regs->LDS, XOR-swizzled); B staged with
//      global_load_lds (linear LDS dest, per-lane pre-swizzled global source
//      so ds_read-side swizzle still sees conflict-free layout).
// XCD swizzle: vid=(bid&7)*128+(bid>>3) -> the 4 blocks sharing an X-panel and
// the 2MB W-split stay on one XCD's L2 (1024 % 8 == 0 -> bijective).

typedef short        bf16x8 __attribute__((ext_vector_type(8)));
typedef float        f32x4  __attribute__((ext_vector_type(4)));
typedef unsigned int u32x2  __attribute__((ext_vector_type(2)));

static constexpr int Mdim = 32768;
static constexpr int Kdim = 512;
static constexpr int Ndim = 512;

__device__ __forceinline__ unsigned cvt_pk_bf16(float a, float b) {
  unsigned r;  // r.lo16 = bf16_rne(a), r.hi16 = bf16_rne(b)
  asm("v_cvt_pk_bf16_f32 %0, %1, %2" : "=v"(r) : "v"(a), "v"(b));
  return r;
}

// Split 4 fp32 into packed-bf16 hi (RNE) and residual lo (RNE of v-hi).
__device__ __forceinline__ void split4(f32x4 v, u32x2& hi, u32x2& lo) {
  unsigned h0 = cvt_pk_bf16(v[0], v[1]);
  unsigned h1 = cvt_pk_bf16(v[2], v[3]);
  float f0 = __uint_as_float(h0 << 16);
  float f1 = __uint_as_float(h0 & 0xFFFF0000u);
  float f2 = __uint_as_float(h1 << 16);
  float f3 = __uint_as_float(h1 & 0xFFFF0000u);
  lo[0] = cvt_pk_bf16(v[0] - f0, v[1] - f1);
  lo[1] = cvt_pk_bf16(v[2] - f2, v[3] - f3);
  hi[0] = h0; hi[1] = h1;
}

__device__ __forceinline__ float fast_tanh(float x) {
  float e = __expf(2.0f * x);
  return 1.0f - 2.0f * __builtin_amdgcn_rcpf(e + 1.0f);
}

__device__ __forceinline__ void glds16(const unsigned short* g, unsigned short* l) {
  __builtin_amdgcn_global_load_lds(
      (const __attribute__((address_space(1))) unsigned int*)g,
      (__attribute__((address_space(3))) unsigned int*)l, 16, 0, 0);
}

// ---------------- pre-pass: split W into bf16 hi/lo ----------------
__global__ __launch_bounds__(256) void split_w(const float* __restrict__ Wm,
                                               unsigned short* __restrict__ whi,
                                               unsigned short* __restrict__ wlo) {
  const int idx = blockIdx.x * 256 + threadIdx.x;   // 65536 float4s = 512*512 floats
  f32x4 v = *(const f32x4*)(Wm + (size_t)idx * 4);
  u32x2 h, l;
  split4(v, h, l);
  *(u32x2*)(whi + (size_t)idx * 4) = h;
  *(u32x2*)(wlo + (size_t)idx * 4) = l;
}

// ---------------- main GEMM (W pre-split path) ----------------
__global__ __launch_bounds__(512, 4) void gemm_ws(
    const float* __restrict__ X,
    const unsigned short* __restrict__ Whi, const unsigned short* __restrict__ Wlo,
    const float* __restrict__ avec, const float* __restrict__ bvec,
    float* __restrict__ out) {
  // LDS planes: 0=Ahi 1=Alo 2=Bhi 3=Blo, each [128 rows][64 bf16] = 16KB.
  // Logical layout (ds_read side): slot s of row r lives at slot (s ^ (r&7)).
  __shared__ unsigned short lds[4][128 * 64];

  const int bid = blockIdx.x;
  const int vid = (bid & 7) * 128 + (bid >> 3);  // XCD-contiguous virtual id
  const int nB  = vid & 3;
  const int mB  = vid >> 2;
  const int tid  = threadIdx.x;
  const int lane = tid & 63;
  const int wid  = tid >> 6;      // 8 waves: 2 (M) x 4 (N); each wave owns 64x32
  const int wm = wid >> 2, wn = wid & 3;

  f32x4 acc[4][2];
#pragma unroll
  for (int i = 0; i < 4; ++i)
#pragma unroll
    for (int j = 0; j < 2; ++j) acc[i][j] = {0.f, 0.f, 0.f, 0.f};

  // ---- A staging map: 512 threads x 4 float4 (128x64 fp32 per K-step) ----
  const int srow  = tid >> 4;     // 0..31 (then +32*i)
  const int scol4 = tid & 15;
  const int kcol  = scol4 * 4;    // bf16/float column 0..60
  const int soff0 = kcol >> 3;    // 16B slot before XOR
  const float* Xb = X + (size_t)mB * 128 * Kdim;

  // ---- B global_load_lds source addresses (pre-swizzled, m173 pattern) ----
  // Wave w issue i fills LDS rows w*16+i*8 .. +7 linearly; lane l covers
  // (rowLocal = l>>3, slotL = l&7). Content wanted at slotL is source slot
  // slotL ^ (row&7) = (l&7) ^ (l>>3)  (row&7 == l>>3 here).
  const int rl = lane >> 3;                 // 0..7
  const int ssl = (lane & 7) ^ rl;          // source slot 0..7
  const int brow0 = nB * 128 + wid * 16 + rl;      // issue 0 row
  const int brow1 = brow0 + 8;                      // issue 1 row
  const unsigned short* srcBhi0 = Whi + (size_t)brow0 * Kdim + ssl * 8;
  const unsigned short* srcBhi1 = Whi + (size_t)brow1 * Kdim + ssl * 8;
  const unsigned short* srcBlo0 = Wlo + (size_t)brow0 * Kdim + ssl * 8;
  const unsigned short* srcBlo1 = Wlo + (size_t)brow1 * Kdim + ssl * 8;
  unsigned short* dstB0 = &lds[0][(wid * 2 + 0) * 512];  // +plane offset below
  unsigned short* dstB1 = &lds[0][(wid * 2 + 1) * 512];
  const int planeSz = 128 * 64;

  // ---- prefetch first A tile ----
  f32x4 rA[4];
#pragma unroll
  for (int i = 0; i < 4; ++i)
    rA[i] = *(const f32x4*)(Xb + (size_t)(srow + 32 * i) * Kdim + kcol);

  for (int kt = 0; kt < Kdim / 64; ++kt) {
    const int kb = kt * 64;
    // B async staging (previous barrier guarantees LDS is free)
    glds16(srcBhi0 + kb, dstB0 + 2 * planeSz);
    glds16(srcBhi1 + kb, dstB1 + 2 * planeSz);
    glds16(srcBlo0 + kb, dstB0 + 3 * planeSz);
    glds16(srcBlo1 + kb, dstB1 + 3 * planeSz);

    // A split + LDS store
#pragma unroll
    for (int i = 0; i < 4; ++i) {
      const int row = srow + 32 * i;
      const int off = row * 64 + ((soff0 ^ (row & 7)) << 3) + (kcol & 7);
      u32x2 h, l;
      split4(rA[i], h, l);
      *(u32x2*)&lds[0][off] = h;
      *(u32x2*)&lds[1][off] = l;
    }
    __syncthreads();   // drains glds (vmcnt) + ds_writes (lgkm)

    // prefetch next A tile (latency hides under MFMA below)
    if (kt != Kdim / 64 - 1) {
#pragma unroll
      for (int i = 0; i < 4; ++i)
        rA[i] = *(const f32x4*)(Xb + (size_t)(srow + 32 * i) * Kdim + kb + 64 + kcol);
    }

    // compute
#pragma unroll
    for (int ks = 0; ks < 2; ++ks) {
      const int slotBase = ks * 4 + (lane >> 4);
      bf16x8 bh[2], bl[2];
#pragma unroll
      for (int ni = 0; ni < 2; ++ni) {
        const int row = wn * 32 + ni * 16 + (lane & 15);
        const int off = row * 64 + ((slotBase ^ (row & 7)) << 3);
        bh[ni] = *(const bf16x8*)&lds[2][off];
        bl[ni] = *(const bf16x8*)&lds[3][off];
      }
#pragma unroll
      for (int mi = 0; mi < 4; ++mi) {
        const int row = wm * 64 + mi * 16 + (lane & 15);
        const int off = row * 64 + ((slotBase ^ (row & 7)) << 3);
        bf16x8 ah = *(const bf16x8*)&lds[0][off];
        bf16x8 al = *(const bf16x8*)&lds[1][off];
#pragma unroll
        for (int ni = 0; ni < 2; ++ni) {
          acc[mi][ni] = __builtin_amdgcn_mfma_f32_16x16x32_bf16(ah, bh[ni], acc[mi][ni], 0, 0, 0);
          acc[mi][ni] = __builtin_amdgcn_mfma_f32_16x16x32_bf16(ah, bl[ni], acc[mi][ni], 0, 0, 0);
          acc[mi][ni] = __builtin_amdgcn_mfma_f32_16x16x32_bf16(al, bh[ni], acc[mi][ni], 0, 0, 0);
        }
      }
    }
    __syncthreads();
  }

  // Epilogue: C/D layout 16x16x32: col = lane&15, row = (lane>>4)*4 + reg.
  const int c  = lane & 15;
  const int rq = (lane >> 4) * 4;
#pragma unroll
  for (int ni = 0; ni < 2; ++ni) {
    const int gc = nB * 128 + wn * 32 + ni * 16 + c;
    const float aa = avec[gc];
    const float bb = bvec[gc];
#pragma unroll
    for (int mi = 0; mi < 4; ++mi) {
      const int gr = mB * 128 + wm * 64 + mi * 16 + rq;
      f32x4 v = acc[mi][ni];
#pragma unroll
      for (int j = 0; j < 4; ++j) {
        out[(size_t)(gr + j) * Ndim + gc] = fast_tanh(aa * v[j] + bb);
      }
    }
  }
}

// ---------------- fallback: round-4 kernel (in-kernel W split) ----------------
__global__ __launch_bounds__(512, 4) void gemm_nows(
    const float* __restrict__ X, const float* __restrict__ Wm,
    const float* __restrict__ avec, const float* __restrict__ bvec,
    float* __restrict__ out) {
  __shared__ unsigned short lds[4][128 * 64];
  const int bid = blockIdx.x;
  const int nB  = bid & 3;
  const int mB  = bid >> 2;
  const int tid  = threadIdx.x;
  const int lane = tid & 63;
  const int wid  = tid >> 6;
  const int wm = wid >> 2, wn = wid & 3;

  f32x4 acc[4][2];
#pragma unroll
  for (int i = 0; i < 4; ++i)
#pragma unroll
    for (int j = 0; j < 2; ++j) acc[i][j] = {0.f, 0.f, 0.f, 0.f};

  const int srow  = tid >> 4;
  const int scol4 = tid & 15;
  const int kcol  = scol4 * 4;
  const int soff0 = kcol >> 3;
  const float* Xb = X  + (size_t)mB * 128 * Kdim;
  const float* Wb = Wm + (size_t)nB * 128 * Kdim;

  f32x4 rA[4], rB[4];
#pragma unroll
  for (int i = 0; i < 4; ++i) {
    const int row = srow + 32 * i;
    rA[i] = *(const f32x4*)(Xb + (size_t)row * Kdim + kcol);
    rB[i] = *(const f32x4*)(Wb + (size_t)row * Kdim + kcol);
  }

  for (int kt = 0; kt < Kdim / 64; ++kt) {
#pragma unroll
    for (int i = 0; i < 4; ++i) {
      const int row = srow + 32 * i;
      const int off = row * 64 + ((soff0 ^ (row & 7)) << 3) + (kcol & 7);
      u32x2 h, l;
      split4(rA[i], h, l);
      *(u32x2*)&lds[0][off] = h;
      *(u32x2*)&lds[1][off] = l;
      split4(rB[i], h, l);
      *(u32x2*)&lds[2][off] = h;
      *(u32x2*)&lds[3][off] = l;
    }
    __syncthreads();
    if (kt != Kdim / 64 - 1) {
      const int kbase = (kt + 1) * 64;
#pragma unroll
      for (int i = 0; i < 4; ++i) {
        const int row = srow + 32 * i;
        rA[i] = *(const f32x4*)(Xb + (size_t)row * Kdim + kbase + kcol);
        rB[i] = *(const f32x4*)(Wb + (size_t)row * Kdim + kbase + kcol);
      }
    }
#pragma unroll
    for (int ks = 0; ks < 2; ++ks) {
      const int slotBase = ks * 4 + (lane >> 4);
      bf16x8 bh[2], bl[2];
#pragma unroll
      for (int ni = 0; ni < 2; ++ni) {
        const int row = wn * 32 + ni * 16 + (lane & 15);
        const int off = row * 64 + ((slotBase ^ (row & 7)) << 3);
        bh[ni] = *(const bf16x8*)&lds[2][off];
        bl[ni] = *(const bf16x8*)&lds[3][off];
      }
#pragma unroll
      for (int mi = 0; mi < 4; ++mi) {
        const int row = wm * 64 + mi * 16 + (lane & 15);
        const int off = row * 64 + ((slotBase ^ (row & 7)) << 3);
        bf16x8 ah = *(const bf16x8*)&lds[0][off];
        bf16x8 al = *(const bf16x8*)&lds[1][off];
#pragma unroll
        for (int ni = 0; ni < 2; ++ni) {
          acc[mi][ni] = __builtin_amdgcn_mfma_f32_16x16x32_bf16(ah, bh[ni], acc[mi][ni], 0, 0, 0);
          acc[mi][ni] = __builtin_amdgcn_mfma_f32_16x16x32_bf16(ah, bl[ni], acc[mi][ni], 0, 0, 0);
          acc[mi][ni] = __builtin_amdgcn_mfma_f32_16x16x32_bf16(al, bh[ni], acc[mi][ni], 0, 0, 0);
        }
      }
    }
    __syncthreads();
  }

  const int c  = lane & 15;
  const int rq = (lane >> 4) * 4;
#pragma unroll
  for (int ni = 0; ni < 2; ++ni) {
    const int gc = nB * 128 + wn * 32 + ni * 16 + c;
    const float aa = avec[gc];
    const float bb = bvec[gc];
#pragma unroll
    for (int mi = 0; mi < 4; ++mi) {
      const int gr = mB * 128 + wm * 64 + mi * 16 + rq;
      f32x4 v = acc[mi][ni];
#pragma unroll
      for (int j = 0; j < 4; ++j) {
        out[(size_t)(gr + j) * Ndim + gc] = fast_tanh(aa * v[j] + bb);
      }
    }
  }
}

extern "C" void kernel_launch(void* const* d_in, const int* in_sizes, int n_in,
                              void* d_out, int out_size, void* d_ws, size_t ws_size,
                              hipStream_t stream) {
  const float* X  = (const float*)d_in[0];
  const float* Wm = (const float*)d_in[1];
  const float* av = (const float*)d_in[2];
  const float* bv = (const float*)d_in[3];
  float* out = (float*)d_out;

  const size_t wSplitBytes = (size_t)Ndim * Kdim * 2 * sizeof(unsigned short); // 1 MB
  if (ws_size >= wSplitBytes) {
    unsigned short* whi = (unsigned short*)d_ws;
    unsigned short* wlo = whi + (size_t)Ndim * Kdim;
    split_w<<<dim3(Ndim * Kdim / 4 / 256), dim3(256), 0, stream>>>(Wm, whi, wlo);
    gemm_ws<<<dim3((Mdim / 128) * (Ndim / 128)), dim3(512), 0, stream>>>(X, whi, wlo, av, bv, out);
  } else {
    gemm_nows<<<dim3((Mdim / 128) * (Ndim / 128)), dim3(512), 0, stream>>>(X, Wm, av, bv, out);
  }
}

// Round 6
// 146.329 us; speedup vs baseline: 1.0799x; 1.0799x over previous
//
#include <hip/hip_runtime.h>
#include <hip/hip_bf16.h>
#include <math.h>

// out[i,f] = tanh(b[f] + a[f] * dot(W[f,:], x[i,:]))
// GEMM M=32768 N=512 K=512. Single-term fp16 MFMA (error analysis: dot-err
// sigma ~4e-4, max*|a| ~6e-3 << 2e-2 threshold; measured exact-GEMM floor 3.9e-3).
// Structure: 128x128 tile, BK=64, 512 thr (8 waves 2Mx4N), DOUBLE-buffered LDS
// (2 x (A 16KB + B 16KB) = 64KB -> 2 blocks/CU), ONE barrier per K-step.
// B: W pre-converted to fp16 in d_ws, staged via global_load_lds with
// pre-swizzled per-lane global source (linear LDS dest). A: fp32 load ->
// in-register fp16 convert -> swizzled ds_write. XOR slot swizzle (measured 0
// bank conflicts). XCD-bijective block swizzle (1024 % 8 == 0).

typedef _Float16     f16x8 __attribute__((ext_vector_type(8)));
typedef float        f32x4 __attribute__((ext_vector_type(4)));
typedef unsigned int u32x2 __attribute__((ext_vector_type(2)));

static constexpr int Mdim = 32768;
static constexpr int Kdim = 512;
static constexpr int Ndim = 512;

__device__ __forceinline__ unsigned pk16(float a, float b) {
  union { _Float16 h; unsigned short u; } ca, cb;
  ca.h = (_Float16)a;  // v_cvt_f16_f32, RNE
  cb.h = (_Float16)b;
  return (unsigned)ca.u | ((unsigned)cb.u << 16);
}

__device__ __forceinline__ float fast_tanh(float x) {
  float e = __expf(2.0f * x);
  return 1.0f - 2.0f * __builtin_amdgcn_rcpf(e + 1.0f);
}

__device__ __forceinline__ void glds16(const unsigned short* g, unsigned short* l) {
  __builtin_amdgcn_global_load_lds(
      (const __attribute__((address_space(1))) unsigned int*)g,
      (__attribute__((address_space(3))) unsigned int*)l, 16, 0, 0);
}

// ---------------- pre-pass: W fp32 -> fp16 ----------------
__global__ __launch_bounds__(256) void conv_w(const float* __restrict__ Wm,
                                              unsigned short* __restrict__ wh) {
  const int idx = blockIdx.x * 256 + threadIdx.x;   // 65536 float4s
  f32x4 v = *(const f32x4*)(Wm + (size_t)idx * 4);
  u32x2 p = { pk16(v[0], v[1]), pk16(v[2], v[3]) };
  *(u32x2*)(wh + (size_t)idx * 4) = p;
}

// ---------------- main GEMM (fp16, double-buffered, 1 barrier/K-step) --------
__global__ __launch_bounds__(512, 4) void gemm_f16(
    const float* __restrict__ X, const unsigned short* __restrict__ Wh,
    const float* __restrict__ avec, const float* __restrict__ bvec,
    float* __restrict__ out) {
  // [buf][plane: 0=A 1=B][128 rows][64 fp16]; slot s of row r at slot s^(r&7).
  __shared__ unsigned short lds[2][2][128 * 64];

  const int bid = blockIdx.x;
  const int vid = (bid & 7) * 128 + (bid >> 3);  // XCD-contiguous, bijective
  const int nB  = vid & 3;
  const int mB  = vid >> 2;
  const int tid  = threadIdx.x;
  const int lane = tid & 63;
  const int wid  = tid >> 6;      // 8 waves: 2(M) x 4(N); wave owns 64x32
  const int wm = wid >> 2, wn = wid & 3;

  f32x4 acc[4][2];
#pragma unroll
  for (int i = 0; i < 4; ++i)
#pragma unroll
    for (int j = 0; j < 2; ++j) acc[i][j] = {0.f, 0.f, 0.f, 0.f};

  // A staging map: 512 threads x 4 float4 (128x64 fp32 per K-step)
  const int srow  = tid >> 4;     // 0..31 (then +32*i)
  const int scol4 = tid & 15;
  const int kcol  = scol4 * 4;    // column 0..60
  const int soff0 = kcol >> 3;    // 16B slot before XOR
  const float* Xb = X + (size_t)mB * 128 * Kdim;

  // B glds: wave w issue i fills rows w*16+i*8..+7 linearly; lane l covers
  // (rowLocal=l>>3, slotL=l&7); source slot = slotL ^ rowLocal (involution).
  const int rl  = lane >> 3;
  const int ssl = (lane & 7) ^ rl;
  const int brow0 = nB * 128 + wid * 16 + rl;
  const unsigned short* sB0 = Wh + (size_t)brow0 * Kdim + ssl * 8;
  const unsigned short* sB1 = Wh + (size_t)(brow0 + 8) * Kdim + ssl * 8;

  // ---- prologue: stage tile 0 into buf 0 ----
  glds16(sB0, &lds[0][1][(wid * 16) * 64]);
  glds16(sB1, &lds[0][1][(wid * 16 + 8) * 64]);
#pragma unroll
  for (int i = 0; i < 4; ++i) {
    const int row = srow + 32 * i;
    f32x4 r = *(const f32x4*)(Xb + (size_t)row * Kdim + kcol);
    const int off = row * 64 + ((soff0 ^ (row & 7)) << 3) + (kcol & 7);
    u32x2 p = { pk16(r[0], r[1]), pk16(r[2], r[3]) };
    *(u32x2*)&lds[0][0][off] = p;
  }
  __syncthreads();

  int cur = 0;
  for (int kt = 0; kt < Kdim / 64; ++kt) {
    const int nxt = cur ^ 1;
    f32x4 rA[4];
    // issue next-tile loads FIRST: latency hides under this iter's MFMAs
    if (kt < Kdim / 64 - 1) {
      const int kb = (kt + 1) * 64;
      glds16(sB0 + kb, &lds[nxt][1][(wid * 16) * 64]);
      glds16(sB1 + kb, &lds[nxt][1][(wid * 16 + 8) * 64]);
#pragma unroll
      for (int i = 0; i < 4; ++i)
        rA[i] = *(const f32x4*)(Xb + (size_t)(srow + 32 * i) * Kdim + kb + kcol);
    }

    // compute on buf[cur]
#pragma unroll
    for (int ks = 0; ks < 2; ++ks) {
      const int slotBase = ks * 4 + (lane >> 4);
      f16x8 bfr[2];
#pragma unroll
      for (int ni = 0; ni < 2; ++ni) {
        const int row = wn * 32 + ni * 16 + (lane & 15);
        const int off = row * 64 + ((slotBase ^ (row & 7)) << 3);
        bfr[ni] = *(const f16x8*)&lds[cur][1][off];
      }
#pragma unroll
      for (int mi = 0; mi < 4; ++mi) {
        const int row = wm * 64 + mi * 16 + (lane & 15);
        const int off = row * 64 + ((slotBase ^ (row & 7)) << 3);
        f16x8 afr = *(const f16x8*)&lds[cur][0][off];
#pragma unroll
        for (int ni = 0; ni < 2; ++ni)
          acc[mi][ni] = __builtin_amdgcn_mfma_f32_16x16x32_f16(afr, bfr[ni], acc[mi][ni], 0, 0, 0);
      }
    }

    // convert+stage A(t+1) (compiler waits vmcnt for rA here, covered by MFMAs)
    if (kt < Kdim / 64 - 1) {
#pragma unroll
      for (int i = 0; i < 4; ++i) {
        const int row = srow + 32 * i;
        const int off = row * 64 + ((soff0 ^ (row & 7)) << 3) + (kcol & 7);
        u32x2 p = { pk16(rA[i][0], rA[i][1]), pk16(rA[i][2], rA[i][3]) };
        *(u32x2*)&lds[nxt][0][off] = p;
      }
    }
    __syncthreads();   // drains glds(vmcnt)+ds_write(lgkm); both issued early
    cur = nxt;
  }

  // Epilogue: C/D layout 16x16x32: col = lane&15, row = (lane>>4)*4 + reg.
  const int c  = lane & 15;
  const int rq = (lane >> 4) * 4;
#pragma unroll
  for (int ni = 0; ni < 2; ++ni) {
    const int gc = nB * 128 + wn * 32 + ni * 16 + c;
    const float aa = avec[gc];
    const float bb = bvec[gc];
#pragma unroll
    for (int mi = 0; mi < 4; ++mi) {
      const int gr = mB * 128 + wm * 64 + mi * 16 + rq;
      f32x4 v = acc[mi][ni];
#pragma unroll
      for (int j = 0; j < 4; ++j) {
        out[(size_t)(gr + j) * Ndim + gc] = fast_tanh(aa * v[j] + bb);
      }
    }
  }
}

// ------------- fallback (ws too small): round-4 bf16 3-term, proven ----------
typedef short bf16x8 __attribute__((ext_vector_type(8)));

__device__ __forceinline__ unsigned cvt_pk_bf16(float a, float b) {
  unsigned r;
  asm("v_cvt_pk_bf16_f32 %0, %1, %2" : "=v"(r) : "v"(a), "v"(b));
  return r;
}
__device__ __forceinline__ void split4(f32x4 v, u32x2& hi, u32x2& lo) {
  unsigned h0 = cvt_pk_bf16(v[0], v[1]);
  unsigned h1 = cvt_pk_bf16(v[2], v[3]);
  float f0 = __uint_as_float(h0 << 16);
  float f1 = __uint_as_float(h0 & 0xFFFF0000u);
  float f2 = __uint_as_float(h1 << 16);
  float f3 = __uint_as_float(h1 & 0xFFFF0000u);
  lo[0] = cvt_pk_bf16(v[0] - f0, v[1] - f1);
  lo[1] = cvt_pk_bf16(v[2] - f2, v[3] - f3);
  hi[0] = h0; hi[1] = h1;
}

__global__ __launch_bounds__(512, 4) void gemm_nows(
    const float* __restrict__ X, const float* __restrict__ Wm,
    const float* __restrict__ avec, const float* __restrict__ bvec,
    float* __restrict__ out) {
  __shared__ unsigned short lds[4][128 * 64];
  const int bid = blockIdx.x;
  const int nB  = bid & 3;
  const int mB  = bid >> 2;
  const int tid  = threadIdx.x;
  const int lane = tid & 63;
  const int wid  = tid >> 6;
  const int wm = wid >> 2, wn = wid & 3;

  f32x4 acc[4][2];
#pragma unroll
  for (int i = 0; i < 4; ++i)
#pragma unroll
    for (int j = 0; j < 2; ++j) acc[i][j] = {0.f, 0.f, 0.f, 0.f};

  const int srow  = tid >> 4;
  const int scol4 = tid & 15;
  const int kcol  = scol4 * 4;
  const int soff0 = kcol >> 3;
  const float* Xb = X  + (size_t)mB * 128 * Kdim;
  const float* Wb = Wm + (size_t)nB * 128 * Kdim;

  f32x4 rA[4], rB[4];
#pragma unroll
  for (int i = 0; i < 4; ++i) {
    const int row = srow + 32 * i;
    rA[i] = *(const f32x4*)(Xb + (size_t)row * Kdim + kcol);
    rB[i] = *(const f32x4*)(Wb + (size_t)row * Kdim + kcol);
  }
  for (int kt = 0; kt < Kdim / 64; ++kt) {
#pragma unroll
    for (int i = 0; i < 4; ++i) {
      const int row = srow + 32 * i;
      const int off = row * 64 + ((soff0 ^ (row & 7)) << 3) + (kcol & 7);
      u32x2 h, l;
      split4(rA[i], h, l);
      *(u32x2*)&lds[0][off] = h;
      *(u32x2*)&lds[1][off] = l;
      split4(rB[i], h, l);
      *(u32x2*)&lds[2][off] = h;
      *(u32x2*)&lds[3][off] = l;
    }
    __syncthreads();
    if (kt != Kdim / 64 - 1) {
      const int kbase = (kt + 1) * 64;
#pragma unroll
      for (int i = 0; i < 4; ++i) {
        const int row = srow + 32 * i;
        rA[i] = *(const f32x4*)(Xb + (size_t)row * Kdim + kbase + kcol);
        rB[i] = *(const f32x4*)(Wb + (size_t)row * Kdim + kbase + kcol);
      }
    }
#pragma unroll
    for (int ks = 0; ks < 2; ++ks) {
      const int slotBase = ks * 4 + (lane >> 4);
      bf16x8 bh[2], bl[2];
#pragma unroll
      for (int ni = 0; ni < 2; ++ni) {
        const int row = wn * 32 + ni * 16 + (lane & 15);
        const int off = row * 64 + ((slotBase ^ (row & 7)) << 3);
        bh[ni] = *(const bf16x8*)&lds[2][off];
        bl[ni] = *(const bf16x8*)&lds[3][off];
      }
#pragma unroll
      for (int mi = 0; mi < 4; ++mi) {
        const int row = wm * 64 + mi * 16 + (lane & 15);
        const int off = row * 64 + ((slotBase ^ (row & 7)) << 3);
        bf16x8 ah = *(const bf16x8*)&lds[0][off];
        bf16x8 al = *(const bf16x8*)&lds[1][off];
#pragma unroll
        for (int ni = 0; ni < 2; ++ni) {
          acc[mi][ni] = __builtin_amdgcn_mfma_f32_16x16x32_bf16(ah, bh[ni], acc[mi][ni], 0, 0, 0);
          acc[mi][ni] = __builtin_amdgcn_mfma_f32_16x16x32_bf16(ah, bl[ni], acc[mi][ni], 0, 0, 0);
          acc[mi][ni] = __builtin_amdgcn_mfma_f32_16x16x32_bf16(al, bh[ni], acc[mi][ni], 0, 0, 0);
        }
      }
    }
    __syncthreads();
  }
  const int c  = lane & 15;
  const int rq = (lane >> 4) * 4;
#pragma unroll
  for (int ni = 0; ni < 2; ++ni) {
    const int gc = nB * 128 + wn * 32 + ni * 16 + c;
    const float aa = avec[gc];
    const float bb = bvec[gc];
#pragma unroll
    for (int mi = 0; mi < 4; ++mi) {
      const int gr = mB * 128 + wm * 64 + mi * 16 + rq;
      f32x4 v = acc[mi][ni];
#pragma unroll
      for (int j = 0; j < 4; ++j) {
        out[(size_t)(gr + j) * Ndim + gc] = fast_tanh(aa * v[j] + bb);
      }
    }
  }
}

extern "C" void kernel_launch(void* const* d_in, const int* in_sizes, int n_in,
                              void* d_out, int out_size, void* d_ws, size_t ws_size,
                              hipStream_t stream) {
  const float* X  = (const float*)d_in[0];
  const float* Wm = (const float*)d_in[1];
  const float* av = (const float*)d_in[2];
  const float* bv = (const float*)d_in[3];
  float* out = (float*)d_out;

  const size_t wBytes = (size_t)Ndim * Kdim * sizeof(unsigned short); // 512 KB
  if (ws_size >= wBytes) {
    unsigned short* wh = (unsigned short*)d_ws;
    conv_w<<<dim3(Ndim * Kdim / 4 / 256), dim3(256), 0, stream>>>(Wm, wh);
    gemm_f16<<<dim3((Mdim / 128) * (Ndim / 128)), dim3(512), 0, stream>>>(X, wh, av, bv, out);
  } else {
    gemm_nows<<<dim3((Mdim / 128) * (Ndim / 128)), dim3(512), 0, stream>>>(X, Wm, av, bv, out);
  }
}